// Round 3
// baseline (609.322 us; speedup 1.0000x reference)
//
#include <hip/hip_runtime.h>
#include <hip/hip_bf16.h>

// Problem geometry
#define N_ROWS 32000   // Q_OUT*Q_IN*NUM_P
#define SB     12      // SCALAR_BASIS
#define FC     720     // FILTER_C
#define FD     2704    // FILTER_DIM
#define KST    2752    // FD padded to 43*64 (BK=64 tiles)
#define NT     43      // K tiles
#define OCOLS  2704    // DIM_OUT*DIM_IN
#define OPAD   2816    // OCOLS padded to 11*256
#define ANGD   25
#define NTILES 1375    // 125 bm * 11 bn
#define GEMM_BLOCKS 256

typedef __attribute__((ext_vector_type(8))) short bf16x8;
typedef __attribute__((ext_vector_type(4))) float f32x4;

__device__ __forceinline__ void gload16(const void* g, void* l) {
    __builtin_amdgcn_global_load_lds(
        (const __attribute__((address_space(1))) void*)g,
        (__attribute__((address_space(3))) void*)l, 16, 0, 0);
}

__device__ __forceinline__ void decode_f(int f, int& c, int& j, int& a) {
    if (f < 144)       { c = f;                         j = 0;            a = 0;  }
    else if (f < 960)  { int t = f - 144;  c = 144 + t/3; j = t - (t/3)*3; a = 1;  }
    else if (f < 2000) { int t = f - 960;  c = 416 + t/5; j = t - (t/5)*5; a = 4;  }
    else if (f < 2560) { int t = f - 2000; c = 624 + t/7; j = t - (t/7)*7; a = 9;  }
    else               { int t = f - 2560; c = 704 + t/9; j = t - (t/9)*9; a = 16; }
}

// ---------------------------------------------------------------------------
// Kernel 1: per-row n, sc = sk @ (W/sqrt(12)); expand to bf16 filt row (KST)
// Vectorized: each thread emits 8 bf16 (16 B) per group.
// ---------------------------------------------------------------------------
__global__ void build_filt(const float* __restrict__ sk,
                           const float* __restrict__ ang,
                           const float* __restrict__ W,
                           __hip_bfloat16* __restrict__ filt)
{
    const int n   = blockIdx.x;
    const int tid = threadIdx.x;  // 256
    __shared__ float s_sc[FC];
    __shared__ float s_ang[ANGD];
    __shared__ float s_sk[SB];

    if (tid < SB) s_sk[tid] = sk[(size_t)n * SB + tid];
    if (tid >= 32 && tid < 32 + ANGD) s_ang[tid - 32] = ang[(size_t)n * ANGD + (tid - 32)];
    __syncthreads();

    const float inv = 0.28867513459481288f; // 1/sqrt(12)
    for (int c = tid; c < FC; c += 256) {
        float acc = 0.f;
        #pragma unroll
        for (int s = 0; s < SB; ++s) acc += s_sk[s] * W[s * FC + c];
        s_sc[c] = acc * inv;
    }
    __syncthreads();

    const size_t base = (size_t)n * KST;
    for (int g = tid; g < KST / 8; g += 256) {
        alignas(16) __hip_bfloat16 tmp[8];
        const int f0 = g * 8;
        #pragma unroll
        for (int u = 0; u < 8; ++u) {
            const int f = f0 + u;
            float v = 0.f;
            if (f < FD) {
                int c, j, a;
                decode_f(f, c, j, a);
                v = s_sc[c] * s_ang[a + j];
            }
            tmp[u] = __float2bfloat16(v);
        }
        *(bf16x8*)(filt + base + f0) = *(const bf16x8*)tmp;
    }
}

// ---------------------------------------------------------------------------
// Kernel 2: TP_mixing (2704x2704 f32) -> bf16 padded (OPAD x KST), pad = 0
// Vectorized: float4 x2 loads, bf16x8 store per thread.
// ---------------------------------------------------------------------------
#define GPR (KST / 8)   // 344 groups per row
__global__ void cvt_M(const float* __restrict__ M, __hip_bfloat16* __restrict__ out)
{
    const int g = blockIdx.x * 256 + threadIdx.x;
    if (g >= OPAD * GPR) return;
    const int o = g / GPR;
    const int k = (g - o * GPR) * 8;
    alignas(16) __hip_bfloat16 tmp[8];
    if (o < OCOLS && k + 8 <= FD) {
        const float4* p = (const float4*)(M + (size_t)o * FD + k);
        float4 x0 = p[0], x1 = p[1];
        tmp[0] = __float2bfloat16(x0.x); tmp[1] = __float2bfloat16(x0.y);
        tmp[2] = __float2bfloat16(x0.z); tmp[3] = __float2bfloat16(x0.w);
        tmp[4] = __float2bfloat16(x1.x); tmp[5] = __float2bfloat16(x1.y);
        tmp[6] = __float2bfloat16(x1.z); tmp[7] = __float2bfloat16(x1.w);
    } else {
        #pragma unroll
        for (int u = 0; u < 8; ++u) {
            float v = (o < OCOLS && k + u < FD) ? M[(size_t)o * FD + k + u] : 0.f;
            tmp[u] = __float2bfloat16(v);
        }
    }
    *(bf16x8*)(out + (size_t)o * KST + k) = *(const bf16x8*)tmp;
}

// ---------------------------------------------------------------------------
// Kernel 3: persistent 256x256-tile 8-phase bf16 GEMM (m201 structure).
// C[n,o] = sum_k A[n,k]*B[o,k]. A:(N_ROWS,KST) B:(OPAD,KST) bf16, C f32.
// grid = 256 blocks (1/CU); block b owns a contiguous balanced run of
// 5-6 tiles (bm-major order -> A-panel L2 reuse across its tiles).
// ---------------------------------------------------------------------------
__global__ __launch_bounds__(512, 2) void gemm_bt(
    const __hip_bfloat16* __restrict__ A,
    const __hip_bfloat16* __restrict__ B,
    float* __restrict__ C)
{
    __shared__ __align__(1024) char lds[131072];
    char* const ldsA = lds;           // 2 buf x 2 half x 16384 B
    char* const ldsB = lds + 65536;

    const int tid  = threadIdx.x;
    const int wave = tid >> 6;
    const int lane = tid & 63;
    const int b    = blockIdx.x;

    // balanced static assignment: 95 blocks x 6 tiles + 161 x 5 = 1375
    const int cnt   = 5 + (b < 95 ? 1 : 0);
    const int start = b * 5 + (b < 95 ? b : 95);

    const int wr = wave >> 2;   // 0..1 (M)
    const int wc = wave & 3;    // 0..3 (N)

    // staging lane constants (LDS linear dest; source pre-swizzled)
    const int lrow  = lane >> 3;
    const int lslot = ((lane & 7) ^ (lrow & 7)) << 4;

    // reader lane constants
    const int rl   = lane & 15;
    const int koct = lane >> 4;
    const int sK0 = ((0 * 4 + koct) ^ (lane & 7)) << 4;
    const int sK1 = ((1 * 4 + koct) ^ (lane & 7)) << 4;
    const int arow = wr * 64 + rl;
    const int brow = (wc & 1) * 64 + rl;
    const int bhalf = wc >> 1;

    for (int ti = 0; ti < cnt; ++ti) {
        const int wg = start + ti;
        const int bm = wg / 11;
        const int bn = wg - bm * 11;
        const size_t arow0 = (size_t)bm * 256;
        const size_t brow0 = (size_t)bn * 256;

        auto STAGE = [&](const char* gbase, size_t growbase, int tile, char* lbase) {
            const char* g0 = gbase + (growbase + (size_t)(wave * 8 + lrow)) * (KST * 2)
                                   + (size_t)tile * 128 + lslot;
            gload16(g0,                          lbase + wave * 1024);
            gload16(g0 + (size_t)64 * (KST * 2), lbase + 8192 + wave * 1024);
        };

        // prologue: tile0 {B0,B1,A0,A1}, tile1 {B0,B1,A0}
        STAGE((const char*)B, brow0 + 0,   0, ldsB + 0);
        STAGE((const char*)B, brow0 + 128, 0, ldsB + 16384);
        STAGE((const char*)A, arow0 + 0,   0, ldsA + 0);
        STAGE((const char*)A, arow0 + 128, 0, ldsA + 16384);
        STAGE((const char*)B, brow0 + 0,   1, ldsB + 32768);
        STAGE((const char*)B, brow0 + 128, 1, ldsB + 32768 + 16384);
        STAGE((const char*)A, arow0 + 0,   1, ldsA + 32768);
        asm volatile("s_waitcnt vmcnt(6)" ::: "memory");
        __builtin_amdgcn_s_barrier();

        f32x4 acc[8][4] = {};   // [q*2+m][n]

        for (int t = 0; t < NT; ++t) {
            char* const aB  = ldsA + (t & 1) * 32768;
            char* const bB  = ldsB + (t & 1) * 32768;
            char* const aBn = ldsA + ((t + 1) & 1) * 32768;

            bf16x8 bfr[4][2];
            #pragma unroll
            for (int q = 0; q < 4; ++q) {
                asm volatile("" ::: "memory");
                __builtin_amdgcn_sched_barrier(0);

                bf16x8 af[2][2];
                char* ah = aB + (q >> 1) * 16384;
                #pragma unroll
                for (int m = 0; m < 2; ++m) {
                    const int r = arow + (q & 1) * 32 + m * 16;
                    af[m][0] = *(const bf16x8*)(ah + r * 128 + sK0);
                    af[m][1] = *(const bf16x8*)(ah + r * 128 + sK1);
                }
                if (q == 0) {
                    char* bh = bB + bhalf * 16384;
                    #pragma unroll
                    for (int n = 0; n < 4; ++n) {
                        bfr[n][0] = *(const bf16x8*)(bh + (brow + n * 16) * 128 + sK0);
                        bfr[n][1] = *(const bf16x8*)(bh + (brow + n * 16) * 128 + sK1);
                    }
                }

                if (q == 0 && t + 1 < NT) STAGE((const char*)A, arow0 + 128, t + 1, aBn + 16384);
                if (q == 1 && t + 2 < NT) STAGE((const char*)B, brow0 + 0,   t + 2, bB + 0);
                if (q == 2 && t + 2 < NT) STAGE((const char*)B, brow0 + 128, t + 2, bB + 16384);
                if (q == 3 && t + 2 < NT) STAGE((const char*)A, arow0 + 0,   t + 2, aB + 0);

                __builtin_amdgcn_s_barrier();
                asm volatile("s_waitcnt lgkmcnt(0)" ::: "memory");
                __builtin_amdgcn_sched_barrier(0);

                __builtin_amdgcn_s_setprio(1);
                #pragma unroll
                for (int ks = 0; ks < 2; ++ks)
                    #pragma unroll
                    for (int m = 0; m < 2; ++m)
                        #pragma unroll
                        for (int n = 0; n < 4; ++n)
                            acc[q * 2 + m][n] = __builtin_amdgcn_mfma_f32_16x16x32_bf16(
                                af[m][ks], bfr[n][ks], acc[q * 2 + m][n], 0, 0, 0);
                __builtin_amdgcn_s_setprio(0);
                __builtin_amdgcn_sched_barrier(0);

                if (q == 3 && t + 1 < NT) {
                    if (t + 1 == NT - 1) asm volatile("s_waitcnt vmcnt(0)" ::: "memory");
                    else                 asm volatile("s_waitcnt vmcnt(6)" ::: "memory");
                }
                __builtin_amdgcn_s_barrier();
            }
        }

        // epilogue: C/D layout col=lane&15, row=(lane>>4)*4+r
        const int ocol0 = (int)brow0 + wc * 64 + rl;
        const int orow_l = (lane >> 4) << 2;
        #pragma unroll
        for (int q = 0; q < 4; ++q)
            #pragma unroll
            for (int m = 0; m < 2; ++m) {
                const int grow = (int)arow0 + (q >> 1) * 128 + wr * 64 + (q & 1) * 32 + m * 16 + orow_l;
                #pragma unroll
                for (int n = 0; n < 4; ++n) {
                    const int gcol = ocol0 + n * 16;
                    if (gcol < OCOLS) {
                        #pragma unroll
                        for (int r = 0; r < 4; ++r)
                            C[(size_t)(grow + r) * OCOLS + gcol] = acc[q * 2 + m][n][r];
                    }
                }
            }
        // no extra barrier needed: all waves passed the final phase barrier
        // before epilogue; epilogue touches no LDS. Next tile's STAGEs are
        // ordered after epilogue stores in each wave's program order, and
        // the prologue vmcnt(6) over-waits (stores inflate vmcnt) -> safe.
    }
}

// ---------------------------------------------------------------------------
extern "C" void kernel_launch(void* const* d_in, const int* in_sizes, int n_in,
                              void* d_out, int out_size, void* d_ws, size_t ws_size,
                              hipStream_t stream)
{
    const float* sk  = (const float*)d_in[0];
    const float* ang = (const float*)d_in[1];
    const float* W   = (const float*)d_in[2];
    const float* TP  = (const float*)d_in[3];
    float* out = (float*)d_out;

    __hip_bfloat16* filt = (__hip_bfloat16*)d_ws;           // N_ROWS*KST bf16
    __hip_bfloat16* Mb   = filt + (size_t)N_ROWS * KST;     // OPAD*KST bf16
    // ws needed: (32000*2752 + 2816*2752)*2 B ~= 192 MiB

    build_filt<<<N_ROWS, 256, 0, stream>>>(sk, ang, W, filt);

    const int totG = OPAD * GPR;
    cvt_M<<<(totG + 255) / 256, 256, 0, stream>>>(TP, Mb);

    gemm_bt<<<GEMM_BLOCKS, 512, 0, stream>>>(filt, Mb, out);
}